// Round 6
// baseline (116.944 us; speedup 1.0000x reference)
//
#include <hip/hip_runtime.h>
#include <hip/hip_bf16.h>
#include <stdint.h>

// ---------------------------------------------------------------------------
// DAReLoss: SupCon(reparam features) + JSD(normalized Gaussian stats)
// B=4096, D=512, N=2B=8192, TAU=1, LAM=1
// Round 6: 128x256 tiles (1056), 8 waves of 64x64 (acc 4x4 = 64 AGPR),
// BK=32 ring-4 LDS, stage distance +3, ONE barrier/unit placed AFTER the
// per-wave vmcnt(6) at phase end (template ordering: reads right after
// barrier, latency hidden under other wave's MFMA). lgkm(0)+sched_barrier
// before MFMA cluster, setprio(1) around it.
// ---------------------------------------------------------------------------

typedef __attribute__((ext_vector_type(4))) float f32x4;
typedef __attribute__((ext_vector_type(8))) short bf16x8;

#define NSLOT 96
#define NU    16        // K / 32 units

// ----------------------------- threefry-2x32 -------------------------------
__device__ __forceinline__ void tf_round(uint32_t& x0, uint32_t& x1, int r){
  x0 += x1;
  x1 = (x1 << r) | (x1 >> (32 - r));
  x1 ^= x0;
}

__device__ __forceinline__ void threefry2x32(uint32_t k0, uint32_t k1,
                                             uint32_t c0, uint32_t c1,
                                             uint32_t& o0, uint32_t& o1){
  uint32_t ks2 = k0 ^ k1 ^ 0x1BD11BDAu;
  uint32_t x0 = c0 + k0, x1 = c1 + k1;
  tf_round(x0,x1,13); tf_round(x0,x1,15); tf_round(x0,x1,26); tf_round(x0,x1,6);
  x0 += k1; x1 += ks2 + 1u;
  tf_round(x0,x1,17); tf_round(x0,x1,29); tf_round(x0,x1,16); tf_round(x0,x1,24);
  x0 += ks2; x1 += k0 + 2u;
  tf_round(x0,x1,13); tf_round(x0,x1,15); tf_round(x0,x1,26); tf_round(x0,x1,6);
  x0 += k0; x1 += k1 + 3u;
  tf_round(x0,x1,17); tf_round(x0,x1,29); tf_round(x0,x1,16); tf_round(x0,x1,24);
  x0 += k1; x1 += ks2 + 4u;
  tf_round(x0,x1,13); tf_round(x0,x1,15); tf_round(x0,x1,26); tf_round(x0,x1,6);
  x0 += ks2; x1 += k0 + 5u;
  o0 = x0; o1 = x1;
}

__device__ __forceinline__ float erfinv_f32(float x){
  float w = -log1pf(-x*x);
  float p;
  if (w < 5.0f){
    w -= 2.5f;
    p = 2.81022636e-08f;
    p = fmaf(p,w, 3.43273939e-07f);
    p = fmaf(p,w,-3.5233877e-06f);
    p = fmaf(p,w,-4.39150654e-06f);
    p = fmaf(p,w, 0.00021858087f);
    p = fmaf(p,w,-0.00125372503f);
    p = fmaf(p,w,-0.00417768164f);
    p = fmaf(p,w, 0.246640727f);
    p = fmaf(p,w, 1.50140941f);
  } else {
    w = sqrtf(w) - 3.0f;
    p = -0.000200214257f;
    p = fmaf(p,w, 0.000100950558f);
    p = fmaf(p,w, 0.00134934322f);
    p = fmaf(p,w,-0.00367342844f);
    p = fmaf(p,w, 0.00573950773f);
    p = fmaf(p,w,-0.0076224613f);
    p = fmaf(p,w, 0.00943887047f);
    p = fmaf(p,w, 1.00167406f);
    p = fmaf(p,w, 2.83297682f);
  }
  return p*x;
}

__device__ __forceinline__ float jax_normal_elem(uint32_t k0, uint32_t k1, uint32_t idx){
  uint32_t p = idx & 0xFFFFFu;
  uint32_t hi = idx >> 20;
  uint32_t o0, o1;
  threefry2x32(k0, k1, p, p + 0x100000u, o0, o1);
  uint32_t bits = hi ? o1 : o0;
  float f = __uint_as_float((bits >> 9) | 0x3F800000u) - 1.0f;
  const float lo = -0.99999994f;
  float v = fmaf(f, 2.0f, lo);
  v = fmaxf(lo, v);
  return 1.41421354f * erfinv_f32(v);
}

__device__ __forceinline__ unsigned short f2bf(float f){
  uint32_t u = __float_as_uint(f);
  u += 0x7FFFu + ((u >> 16) & 1u);   // RNE
  return (unsigned short)(u >> 16);
}

// ------------------- K1: features + normalize + JSD (fused) ----------------
__global__ __launch_bounds__(256) void k_featsjsd(const float* __restrict__ mu,
                                                  const float* __restrict__ mu_cap,
                                                  const float* __restrict__ lv,
                                                  const float* __restrict__ lv_cap,
                                                  unsigned short* __restrict__ Xn,
                                                  float* __restrict__ jsd_row){
  int r = blockIdx.x;
  int t = threadIdx.x;
  size_t base = (size_t)r * 512;

  uint32_t a0,a1,b0,b1;
  threefry2x32(0u, 42u, 0u, 2u, a0, b0);
  threefry2x32(0u, 42u, 1u, 3u, a1, b1);

  float2 m2  = *(const float2*)(mu     + base + 2*t);
  float2 mc2 = *(const float2*)(mu_cap + base + 2*t);
  float2 av2 = *(const float2*)(lv     + base + 2*t);
  float2 bv2 = *(const float2*)(lv_cap + base + 2*t);
  float m[2]  = {m2.x,  m2.y};
  float mc[2] = {mc2.x, mc2.y};
  float av[2] = {av2.x, av2.y};
  float bv[2] = {bv2.x, bv2.y};

  float x[2], xc[2];
  float sx=0.f, sxc=0.f, sm=0.f, smc=0.f, sa=0.f, sb=0.f;
  #pragma unroll
  for (int q = 0; q < 2; ++q){
    sm  += m[q]*m[q];   smc += mc[q]*mc[q];
    sa  += av[q]*av[q]; sb  += bv[q]*bv[q];
    uint32_t idx = (uint32_t)r*512u + (uint32_t)(2*t + q);
    float e1 = jax_normal_elem(a0, a1, idx);
    float e2 = jax_normal_elem(b0, b1, idx);
    x[q]  = m[q]  + __expf(0.5f*av[q]) * e1;  sx  += x[q]*x[q];
    xc[q] = mc[q] + __expf(0.5f*bv[q]) * e2;  sxc += xc[q]*xc[q];
  }

  __shared__ float sred[4][6];
  #pragma unroll
  for (int o = 32; o; o >>= 1){
    sx  += __shfl_down(sx,  o);  sxc += __shfl_down(sxc, o);
    sm  += __shfl_down(sm,  o);  smc += __shfl_down(smc, o);
    sa  += __shfl_down(sa,  o);  sb  += __shfl_down(sb,  o);
  }
  if ((t & 63) == 0){
    int w = t >> 6;
    sred[w][0]=sx; sred[w][1]=sxc; sred[w][2]=sm;
    sred[w][3]=smc; sred[w][4]=sa; sred[w][5]=sb;
  }
  __syncthreads();
  float tx  = sred[0][0]+sred[1][0]+sred[2][0]+sred[3][0];
  float txc = sred[0][1]+sred[1][1]+sred[2][1]+sred[3][1];
  float tm  = sred[0][2]+sred[1][2]+sred[2][2]+sred[3][2];
  float tmc = sred[0][3]+sred[1][3]+sred[2][3]+sred[3][3];
  float ta  = sred[0][4]+sred[1][4]+sred[2][4]+sred[3][4];
  float tb  = sred[0][5]+sred[1][5]+sred[2][5]+sred[3][5];
  float ix  = 1.f / fmaxf(sqrtf(tx),  1e-12f);
  float ixc = 1.f / fmaxf(sqrtf(txc), 1e-12f);
  float im  = 1.f / fmaxf(sqrtf(tm),  1e-12f);
  float imc = 1.f / fmaxf(sqrtf(tmc), 1e-12f);
  float ia  = 1.f / fmaxf(sqrtf(ta),  1e-12f);
  float ib  = 1.f / fmaxf(sqrtf(tb),  1e-12f);

  unsigned short xb[2], xcb[2];
  float accv = 0.f;
  #pragma unroll
  for (int q = 0; q < 2; ++q){
    xb[q]  = f2bf(x[q]  * ix);
    xcb[q] = f2bf(xc[q] * ixc);
    float an = m[q]*im, bn = mc[q]*imc;
    float al = av[q]*ia, bl = bv[q]*ib;
    float ea = __expf(al), eb = __expf(bl);
    float varm = 0.5f*(ea + eb);
    float lvm  = __logf(varm + 1e-8f);
    float v2   = __expf(lvm);
    float den  = v2 + 1e-8f;
    float dm   = 0.5f*(an - bn);
    float dm2  = dm*dm;
    float t1 = (ea + 1e-8f)/den + (lvm - al) + dm2/den - 1.f;
    float t2 = (eb + 1e-8f)/den + (lvm - bl) + dm2/den - 1.f;
    accv += t1 + t2;
  }
  *(uint32_t*)&Xn[base + 2*t]                   = *(uint32_t*)xb;
  *(uint32_t*)&Xn[(size_t)(4096 + r)*512 + 2*t] = *(uint32_t*)xcb;

  __shared__ float sred2[4];
  #pragma unroll
  for (int o = 32; o; o >>= 1) accv += __shfl_down(accv, o);
  if ((t & 63) == 0) sred2[t >> 6] = accv;
  __syncthreads();
  if (t == 0)
    jsd_row[r] = 0.25f * (sred2[0]+sred2[1]+sred2[2]+sred2[3]);
}

// -------------------- K2: sim = Xn Xn^T (triangular), LSE ------------------
// 1056 tiles: i in [0,64) x 128 rows, j in [0,32) x 256 cols, j >= i>>1;
// element predicate c>r counts each unordered pair once (rsum slot j,
// csum slot 32+i). 8 waves (2wr x 4wn), wave tile 64x64, acc 4x4 (64 AGPR).
// Ring-4 BK=32 units; per wave per phase: 1 A-gload + 2 B-gloads, stage
// distance +3 (slot (u+3)&3 = (u-1)&3, readers done at phase u-1's barrier).
// Hazards: H1 cross-wave RAW covered by {own vmcnt -> barrier} at phase end;
// H2 WAR: stage(u+3) after barrier(u-1) > last reads of u-1 (lgkm0 pre-MFMA);
// H3 WAW: stage(u-1) retired by vmcnt at end of u-2. Swizzle: verified
// 0-conflict (rounds 3-5 PMC).
__device__ __forceinline__ void gload_lds16(const unsigned short* g, unsigned short* l){
  __builtin_amdgcn_global_load_lds(
      (const __attribute__((address_space(1))) void*)g,
      (__attribute__((address_space(3))) void*)l, 16, 0, 0);
}

__device__ __forceinline__ void stage_chunk(const unsigned short* __restrict__ Xn,
                                            unsigned short* dst, int grow_base,
                                            int u, int prow, int pcol){
  const unsigned short* g = Xn + (size_t)(grow_base + prow)*512 + u*32 + pcol;
  gload_lds16(g, dst);
}

__global__ __launch_bounds__(512, 2) void k_simlse(const unsigned short* __restrict__ Xn,
                                                   float* __restrict__ rowsumP, // [NSLOT][8192]
                                                   float* __restrict__ possim){ // [8192]
  // XCD-chunked bijective swizzle: 1056 = 8*132
  int bid = (blockIdx.x & 7)*132 + (blockIdx.x >> 3);
  // decode -> (i,j): for k in [0,32): i in {2k,2k+1}, j in [k,32)
  int id = bid, kk2 = 0;
  while (id >= 2*(32-kk2)){ id -= 2*(32-kk2); ++kk2; }
  int i = 2*kk2 + (id & 1);
  int j = kk2 + (id >> 1);
  int rowbase = i*128, colbase = j*256;

  __shared__ unsigned short SA[4*4096];   // 4 slots x [128][32] bf16 (32 KB)
  __shared__ unsigned short SB[4*8192];   // 4 slots x [256][32] bf16 (64 KB)
  __shared__ float redR[4][128];          // 2 KB
  __shared__ float redC[2][256];          // 2 KB

  int tid = threadIdx.x;
  int wid = tid >> 6, l = tid & 63;
  int wr = wid >> 2, wn = wid & 3;        // 2 x 4 wave grid, wave tile 64x64
  int l15 = l & 15, l4 = l >> 4;

  // staging source pre-swizzle (per-lane constants; verified 0-conflict)
  int prow = (l >> 3)*2 + (((l & 7) ^ (l >> 3)) >> 2);
  int pcol = (((l & 7) ^ (l >> 3)) & 3) * 8;

  // ds_read frag addressing within a 16x32 chunk (ushort units)
  const int idx8  = (((l15 & 1) << 2) | l4) ^ (l15 >> 1);
  const int rdoff = (l15 >> 1)*64 + idx8*8;

  f32x4 acc[4][4];
  #pragma unroll
  for (int m = 0; m < 4; ++m)
    #pragma unroll
    for (int n = 0; n < 4; ++n) acc[m][n] = f32x4{0.f,0.f,0.f,0.f};

  // ---- prologue: stage units 0,1,2 (3 gloads/wave each) ----
  #pragma unroll
  for (int g0 = 0; g0 < 3; ++g0){
    stage_chunk(Xn, &SA[g0*4096 + wid*512],       rowbase + wid*16,       g0, prow, pcol);
    stage_chunk(Xn, &SB[g0*8192 + (2*wid  )*512], colbase + (2*wid  )*16, g0, prow, pcol);
    stage_chunk(Xn, &SB[g0*8192 + (2*wid+1)*512], colbase + (2*wid+1)*16, g0, prow, pcol);
  }
  // own outstanding = 9; retire stage(0)'s 3 -> vmcnt(6), then barrier makes
  // all waves' unit-0 chunks visible.
  asm volatile("s_waitcnt vmcnt(6)" ::: "memory");
  __builtin_amdgcn_s_barrier();

  // ---- main loop: 16 units of BK=32, ONE barrier per unit (at end) ----
  for (int u = 0; u < NU; ++u){
    int slot = u & 3;
    const unsigned short* SAb = &SA[slot*4096];
    const unsigned short* SBb = &SB[slot*8192];

    bf16x8 af[4], bfr[4];
    #pragma unroll
    for (int m = 0; m < 4; ++m)
      af[m] = *(const bf16x8*)&SAb[(wr*4 + m)*512 + rdoff];
    #pragma unroll
    for (int n = 0; n < 4; ++n)
      bfr[n] = *(const bf16x8*)&SBb[(wn*4 + n)*512 + rdoff];

    int su = u + 3;
    if (su < NU){
      int ss = su & 3;
      stage_chunk(Xn, &SA[ss*4096 + wid*512],       rowbase + wid*16,       su, prow, pcol);
      stage_chunk(Xn, &SB[ss*8192 + (2*wid  )*512], colbase + (2*wid  )*16, su, prow, pcol);
      stage_chunk(Xn, &SB[ss*8192 + (2*wid+1)*512], colbase + (2*wid+1)*16, su, prow, pcol);
    }

    asm volatile("s_waitcnt lgkmcnt(0)" ::: "memory");
    __builtin_amdgcn_sched_barrier(0);
    __builtin_amdgcn_s_setprio(1);
    #pragma unroll
    for (int m = 0; m < 4; ++m)
      #pragma unroll
      for (int n = 0; n < 4; ++n)
        acc[m][n] = __builtin_amdgcn_mfma_f32_16x16x32_bf16(af[m], bfr[n], acc[m][n], 0, 0, 0);
    __builtin_amdgcn_s_setprio(0);

    if (u < NU-1){
      // ledger (own loads): after stage-issue above, outstanding =
      // stage(u+1), stage(u+2), stage(u+3) = 9 -> retire stage(u+1): vmcnt(6).
      // u=13: {s14,s15}=6 -> vmcnt(3); u=14: {s15}=3 -> vmcnt(0).
      if (u < 13)       asm volatile("s_waitcnt vmcnt(6)" ::: "memory");
      else if (u == 13) asm volatile("s_waitcnt vmcnt(3)" ::: "memory");
      else              asm volatile("s_waitcnt vmcnt(0)" ::: "memory");
      __builtin_amdgcn_s_barrier();
    }
  }

  // ---- epilogue: c>r predicate, exp, pos-pair, row/col partial sums ----
  float rsum[4][4];
  float csum[4] = {0.f, 0.f, 0.f, 0.f};
  #pragma unroll
  for (int m = 0; m < 4; ++m)
    #pragma unroll
    for (int rr = 0; rr < 4; ++rr) rsum[m][rr] = 0.f;

  #pragma unroll
  for (int m = 0; m < 4; ++m){
    #pragma unroll
    for (int n = 0; n < 4; ++n){
      int c = colbase + wn*64 + n*16 + l15;
      #pragma unroll
      for (int rr = 0; rr < 4; ++rr){
        int r = rowbase + wr*64 + m*16 + l4*4 + rr;
        float v = acc[m][n][rr];
        if (c - r == 4096){
          possim[r] = v;
          possim[c] = v;
        }
        float e = (c > r) ? __expf(v) : 0.f;
        rsum[m][rr] += e;
        csum[n]     += e;
      }
    }
  }

  // row-sums: reduce across 16 col-lanes; 4 wn-waves combine via LDS; slot j
  #pragma unroll
  for (int m = 0; m < 4; ++m){
    #pragma unroll
    for (int rr = 0; rr < 4; ++rr){
      float s = rsum[m][rr];
      s += __shfl_xor(s, 1); s += __shfl_xor(s, 2);
      s += __shfl_xor(s, 4); s += __shfl_xor(s, 8);
      if (l15 == 0) redR[wn][wr*64 + m*16 + l4*4 + rr] = s;
    }
  }
  // col-sums: reduce across l4 groups; 2 wr-waves combine via LDS; slot 32+i
  #pragma unroll
  for (int n = 0; n < 4; ++n){
    float s = csum[n];
    s += __shfl_xor(s, 16); s += __shfl_xor(s, 32);
    if (l4 == 0) redC[wr][wn*64 + n*16 + l15] = s;
  }
  __syncthreads();
  if (tid < 128){
    float rs = redR[0][tid] + redR[1][tid] + redR[2][tid] + redR[3][tid];
    rowsumP[(size_t)j*8192 + rowbase + tid] = rs;
  }
  if (tid < 256){
    float cs = redC[0][tid] + redC[1][tid];
    rowsumP[(size_t)(32 + i)*8192 + colbase + tid] = cs;
  }
}

// ------------------- K3a: per-256-row (lse - pos) partials ------------------
__global__ __launch_bounds__(256) void k_lsepart(const float* __restrict__ rowsumP,
                                                 const float* __restrict__ possim,
                                                 float* __restrict__ part){
  int i = blockIdx.x*256 + threadIdx.x;
  float s = 0.f;
  #pragma unroll 8
  for (int cs = 0; cs < NSLOT; ++cs) s += rowsumP[(size_t)cs*8192 + i];
  float v = __logf(s) - possim[i];

  __shared__ float sred[4];
  int t = threadIdx.x;
  #pragma unroll
  for (int o = 32; o; o >>= 1) v += __shfl_down(v, o);
  if ((t & 63) == 0) sred[t >> 6] = v;
  __syncthreads();
  if (t == 0) part[blockIdx.x] = sred[0]+sred[1]+sred[2]+sred[3];
}

// --------------------------- K3b: final combine -----------------------------
__global__ __launch_bounds__(256) void k_final(const float* __restrict__ part,
                                               const float* __restrict__ jsd_row,
                                               float* __restrict__ out){
  int t = threadIdx.x;
  float s = (t < 32) ? part[t] : 0.f;
  float j = 0.f;
  #pragma unroll
  for (int q = 0; q < 16; ++q) j += jsd_row[t + q*256];

  __shared__ float sr[4], jr[4];
  float ss = s, jj = j;
  #pragma unroll
  for (int o = 32; o; o >>= 1){ ss += __shfl_down(ss, o); jj += __shfl_down(jj, o); }
  if ((t & 63) == 0){ sr[t >> 6] = ss; jr[t >> 6] = jj; }
  __syncthreads();
  if (t == 0){
    float base = (sr[0]+sr[1]+sr[2]+sr[3]) / (8192.f * (1.f + 1e-5f));
    float jsd  = (jr[0]+jr[1]+jr[2]+jr[3]) / 4096.f;
    out[0] = base + jsd;   // LAM = 1
  }
}

// ---------------------------------------------------------------------------
extern "C" void kernel_launch(void* const* d_in, const int* in_sizes, int n_in,
                              void* d_out, int out_size, void* d_ws, size_t ws_size,
                              hipStream_t stream) {
  const float* mu     = (const float*)d_in[0];
  const float* mu_cap = (const float*)d_in[1];
  const float* lv     = (const float*)d_in[2];
  const float* lv_cap = (const float*)d_in[3];
  float* out = (float*)d_out;

  char* w = (char*)d_ws;
  unsigned short* Xn = (unsigned short*)w;                    // 8192*512*2 = 8 MB
  float* rowsumP = (float*)(w + 8388608);                     // 96*8192*4 = 3 MB
  float* possim  = (float*)(w + 8388608 + 3145728);           // 32 KB
  float* jsd_row = (float*)(w + 8388608 + 3145728 + 32768);   // 16 KB
  float* part    = (float*)(w + 8388608 + 3145728 + 32768 + 16384); // 128 B

  hipMemsetAsync(rowsumP, 0, (size_t)NSLOT*8192*4, stream);
  k_featsjsd<<<4096, 256, 0, stream>>>(mu, mu_cap, lv, lv_cap, Xn, jsd_row);
  k_simlse  <<<1056, 512, 0, stream>>>(Xn, rowsumP, possim);
  k_lsepart <<<32,   256, 0, stream>>>(rowsumP, possim, part);
  k_final   <<<1,    256, 0, stream>>>(part, jsd_row, out);
}

// Round 7
// 111.696 us; speedup vs baseline: 1.0470x; 1.0470x over previous
//
#include <hip/hip_runtime.h>
#include <hip/hip_bf16.h>
#include <stdint.h>

// ---------------------------------------------------------------------------
// DAReLoss: SupCon(reparam features) + JSD(normalized Gaussian stats)
// B=4096, D=512, N=2B=8192, TAU=1, LAM=1
// Round 7: r5 geometry (128x256 tiles, 1056 blocks, 4 waves of 128x64,
// ring-3 BK=32, 2 blocks/CU) + TRUE m201 phase structure: per unit,
// 2 x {barrier; counted lgkm; setprio; 16 MFMA} with all ds_reads and
// stage-gloads issued up front; counted vmcnt(6) ledger; T2 swizzle and
// T5 setprio now operating in their required regime (fine interleave).
// ---------------------------------------------------------------------------

typedef __attribute__((ext_vector_type(4))) float f32x4;
typedef __attribute__((ext_vector_type(8))) short bf16x8;

#define NSLOT 96
#define NU    16        // K / 32 units

// ----------------------------- threefry-2x32 -------------------------------
__device__ __forceinline__ void tf_round(uint32_t& x0, uint32_t& x1, int r){
  x0 += x1;
  x1 = (x1 << r) | (x1 >> (32 - r));
  x1 ^= x0;
}

__device__ __forceinline__ void threefry2x32(uint32_t k0, uint32_t k1,
                                             uint32_t c0, uint32_t c1,
                                             uint32_t& o0, uint32_t& o1){
  uint32_t ks2 = k0 ^ k1 ^ 0x1BD11BDAu;
  uint32_t x0 = c0 + k0, x1 = c1 + k1;
  tf_round(x0,x1,13); tf_round(x0,x1,15); tf_round(x0,x1,26); tf_round(x0,x1,6);
  x0 += k1; x1 += ks2 + 1u;
  tf_round(x0,x1,17); tf_round(x0,x1,29); tf_round(x0,x1,16); tf_round(x0,x1,24);
  x0 += ks2; x1 += k0 + 2u;
  tf_round(x0,x1,13); tf_round(x0,x1,15); tf_round(x0,x1,26); tf_round(x0,x1,6);
  x0 += k0; x1 += k1 + 3u;
  tf_round(x0,x1,17); tf_round(x0,x1,29); tf_round(x0,x1,16); tf_round(x0,x1,24);
  x0 += k1; x1 += ks2 + 4u;
  tf_round(x0,x1,13); tf_round(x0,x1,15); tf_round(x0,x1,26); tf_round(x0,x1,6);
  x0 += ks2; x1 += k0 + 5u;
  o0 = x0; o1 = x1;
}

__device__ __forceinline__ float erfinv_f32(float x){
  float w = -log1pf(-x*x);
  float p;
  if (w < 5.0f){
    w -= 2.5f;
    p = 2.81022636e-08f;
    p = fmaf(p,w, 3.43273939e-07f);
    p = fmaf(p,w,-3.5233877e-06f);
    p = fmaf(p,w,-4.39150654e-06f);
    p = fmaf(p,w, 0.00021858087f);
    p = fmaf(p,w,-0.00125372503f);
    p = fmaf(p,w,-0.00417768164f);
    p = fmaf(p,w, 0.246640727f);
    p = fmaf(p,w, 1.50140941f);
  } else {
    w = sqrtf(w) - 3.0f;
    p = -0.000200214257f;
    p = fmaf(p,w, 0.000100950558f);
    p = fmaf(p,w, 0.00134934322f);
    p = fmaf(p,w,-0.00367342844f);
    p = fmaf(p,w, 0.00573950773f);
    p = fmaf(p,w,-0.0076224613f);
    p = fmaf(p,w, 0.00943887047f);
    p = fmaf(p,w, 1.00167406f);
    p = fmaf(p,w, 2.83297682f);
  }
  return p*x;
}

__device__ __forceinline__ float jax_normal_elem(uint32_t k0, uint32_t k1, uint32_t idx){
  uint32_t p = idx & 0xFFFFFu;
  uint32_t hi = idx >> 20;
  uint32_t o0, o1;
  threefry2x32(k0, k1, p, p + 0x100000u, o0, o1);
  uint32_t bits = hi ? o1 : o0;
  float f = __uint_as_float((bits >> 9) | 0x3F800000u) - 1.0f;
  const float lo = -0.99999994f;
  float v = fmaf(f, 2.0f, lo);
  v = fmaxf(lo, v);
  return 1.41421354f * erfinv_f32(v);
}

__device__ __forceinline__ unsigned short f2bf(float f){
  uint32_t u = __float_as_uint(f);
  u += 0x7FFFu + ((u >> 16) & 1u);   // RNE
  return (unsigned short)(u >> 16);
}

// ------------------- K1: features + normalize + JSD (fused) ----------------
__global__ __launch_bounds__(256) void k_featsjsd(const float* __restrict__ mu,
                                                  const float* __restrict__ mu_cap,
                                                  const float* __restrict__ lv,
                                                  const float* __restrict__ lv_cap,
                                                  unsigned short* __restrict__ Xn,
                                                  float* __restrict__ jsd_row){
  int r = blockIdx.x;
  int t = threadIdx.x;
  size_t base = (size_t)r * 512;

  uint32_t a0,a1,b0,b1;
  threefry2x32(0u, 42u, 0u, 2u, a0, b0);
  threefry2x32(0u, 42u, 1u, 3u, a1, b1);

  float2 m2  = *(const float2*)(mu     + base + 2*t);
  float2 mc2 = *(const float2*)(mu_cap + base + 2*t);
  float2 av2 = *(const float2*)(lv     + base + 2*t);
  float2 bv2 = *(const float2*)(lv_cap + base + 2*t);
  float m[2]  = {m2.x,  m2.y};
  float mc[2] = {mc2.x, mc2.y};
  float av[2] = {av2.x, av2.y};
  float bv[2] = {bv2.x, bv2.y};

  float x[2], xc[2];
  float sx=0.f, sxc=0.f, sm=0.f, smc=0.f, sa=0.f, sb=0.f;
  #pragma unroll
  for (int q = 0; q < 2; ++q){
    sm  += m[q]*m[q];   smc += mc[q]*mc[q];
    sa  += av[q]*av[q]; sb  += bv[q]*bv[q];
    uint32_t idx = (uint32_t)r*512u + (uint32_t)(2*t + q);
    float e1 = jax_normal_elem(a0, a1, idx);
    float e2 = jax_normal_elem(b0, b1, idx);
    x[q]  = m[q]  + __expf(0.5f*av[q]) * e1;  sx  += x[q]*x[q];
    xc[q] = mc[q] + __expf(0.5f*bv[q]) * e2;  sxc += xc[q]*xc[q];
  }

  __shared__ float sred[4][6];
  #pragma unroll
  for (int o = 32; o; o >>= 1){
    sx  += __shfl_down(sx,  o);  sxc += __shfl_down(sxc, o);
    sm  += __shfl_down(sm,  o);  smc += __shfl_down(smc, o);
    sa  += __shfl_down(sa,  o);  sb  += __shfl_down(sb,  o);
  }
  if ((t & 63) == 0){
    int w = t >> 6;
    sred[w][0]=sx; sred[w][1]=sxc; sred[w][2]=sm;
    sred[w][3]=smc; sred[w][4]=sa; sred[w][5]=sb;
  }
  __syncthreads();
  float tx  = sred[0][0]+sred[1][0]+sred[2][0]+sred[3][0];
  float txc = sred[0][1]+sred[1][1]+sred[2][1]+sred[3][1];
  float tm  = sred[0][2]+sred[1][2]+sred[2][2]+sred[3][2];
  float tmc = sred[0][3]+sred[1][3]+sred[2][3]+sred[3][3];
  float ta  = sred[0][4]+sred[1][4]+sred[2][4]+sred[3][4];
  float tb  = sred[0][5]+sred[1][5]+sred[2][5]+sred[3][5];
  float ix  = 1.f / fmaxf(sqrtf(tx),  1e-12f);
  float ixc = 1.f / fmaxf(sqrtf(txc), 1e-12f);
  float im  = 1.f / fmaxf(sqrtf(tm),  1e-12f);
  float imc = 1.f / fmaxf(sqrtf(tmc), 1e-12f);
  float ia  = 1.f / fmaxf(sqrtf(ta),  1e-12f);
  float ib  = 1.f / fmaxf(sqrtf(tb),  1e-12f);

  unsigned short xb[2], xcb[2];
  float accv = 0.f;
  #pragma unroll
  for (int q = 0; q < 2; ++q){
    xb[q]  = f2bf(x[q]  * ix);
    xcb[q] = f2bf(xc[q] * ixc);
    float an = m[q]*im, bn = mc[q]*imc;
    float al = av[q]*ia, bl = bv[q]*ib;
    float ea = __expf(al), eb = __expf(bl);
    float varm = 0.5f*(ea + eb);
    float lvm  = __logf(varm + 1e-8f);
    float v2   = __expf(lvm);
    float den  = v2 + 1e-8f;
    float dm   = 0.5f*(an - bn);
    float dm2  = dm*dm;
    float t1 = (ea + 1e-8f)/den + (lvm - al) + dm2/den - 1.f;
    float t2 = (eb + 1e-8f)/den + (lvm - bl) + dm2/den - 1.f;
    accv += t1 + t2;
  }
  *(uint32_t*)&Xn[base + 2*t]                   = *(uint32_t*)xb;
  *(uint32_t*)&Xn[(size_t)(4096 + r)*512 + 2*t] = *(uint32_t*)xcb;

  __shared__ float sred2[4];
  #pragma unroll
  for (int o = 32; o; o >>= 1) accv += __shfl_down(accv, o);
  if ((t & 63) == 0) sred2[t >> 6] = accv;
  __syncthreads();
  if (t == 0)
    jsd_row[r] = 0.25f * (sred2[0]+sred2[1]+sred2[2]+sred2[3]);
}

// -------------------- K2: sim = Xn Xn^T (triangular), LSE ------------------
// 1056 tiles: i in [0,64) x 128 rows, j in [0,32) x 256 cols, j >= i>>1;
// c>r predicate counts each unordered pair once (rsum slot j, csum slot 32+i).
// 4 waves (1x4), wave tile 128x64, acc 8x4 (128 AGPR). Ring-3 BK=32 slots,
// 6 gloads/wave/unit, stage distance +2, vmcnt(6) ledger (r5-verified).
// Per unit: all 12 ds_reads + 6 gloads issued up front, then
//   barrier; lgkm(4); 16 MFMA (m0-3); barrier; lgkm(0); 16 MFMA (m4-7);
//   vmcnt(6); barrier.
__device__ __forceinline__ void gload_lds16(const unsigned short* g, unsigned short* l){
  __builtin_amdgcn_global_load_lds(
      (const __attribute__((address_space(1))) void*)g,
      (__attribute__((address_space(3))) void*)l, 16, 0, 0);
}

__device__ __forceinline__ void stage_chunk(const unsigned short* __restrict__ Xn,
                                            unsigned short* dst, int grow_base,
                                            int u, int prow, int pcol){
  const unsigned short* g = Xn + (size_t)(grow_base + prow)*512 + u*32 + pcol;
  gload_lds16(g, dst);
}

__global__ __launch_bounds__(256, 2) void k_simlse(const unsigned short* __restrict__ Xn,
                                                   float* __restrict__ rowsumP, // [NSLOT][8192]
                                                   float* __restrict__ possim){ // [8192]
  // XCD-chunked bijective swizzle: 1056 = 8*132
  int bid = (blockIdx.x & 7)*132 + (blockIdx.x >> 3);
  // decode -> (i,j): for k in [0,32): i in {2k,2k+1}, j in [k,32)
  int id = bid, kk2 = 0;
  while (id >= 2*(32-kk2)){ id -= 2*(32-kk2); ++kk2; }
  int i = 2*kk2 + (id & 1);
  int j = kk2 + (id >> 1);
  int rowbase = i*128, colbase = j*256;

  __shared__ unsigned short SA[3*4096];   // 3 slots x 8 chunks x 512 (24 KB)
  __shared__ unsigned short SB[3*8192];   // 3 slots x 16 chunks x 512 (48 KB)
  __shared__ float redR[4][128];          // 2 KB

  int tid = threadIdx.x;
  int wid = tid >> 6, l = tid & 63;       // 4 waves; wn = wid (1x4 grid)
  int wn = wid;
  int l15 = l & 15, l4 = l >> 4;

  // staging source pre-swizzle (per-lane constants; verified 0-conflict)
  int prow = (l >> 3)*2 + (((l & 7) ^ (l >> 3)) >> 2);
  int pcol = (((l & 7) ^ (l >> 3)) & 3) * 8;

  // ds_read frag addressing within a 16x32 chunk (ushort units)
  const int idx8  = (((l15 & 1) << 2) | l4) ^ (l15 >> 1);
  const int rdoff = (l15 >> 1)*64 + idx8*8;

  f32x4 acc[8][4];
  #pragma unroll
  for (int m = 0; m < 8; ++m)
    #pragma unroll
    for (int n = 0; n < 4; ++n) acc[m][n] = f32x4{0.f,0.f,0.f,0.f};

  // ---- prologue: stage units 0,1 (6 gloads/wave each) ----
  #pragma unroll
  for (int g0 = 0; g0 < 2; ++g0){
    stage_chunk(Xn, &SA[g0*4096 + (2*wid  )*512], rowbase + (2*wid  )*16, g0, prow, pcol);
    stage_chunk(Xn, &SA[g0*4096 + (2*wid+1)*512], rowbase + (2*wid+1)*16, g0, prow, pcol);
    #pragma unroll
    for (int q = 0; q < 4; ++q)
      stage_chunk(Xn, &SB[g0*8192 + (4*wid+q)*512], colbase + (4*wid+q)*16, g0, prow, pcol);
  }
  // outstanding = 12; retire stage(0): vmcnt(6); publish slot 0.
  asm volatile("s_waitcnt vmcnt(6)" ::: "memory");
  __builtin_amdgcn_s_barrier();

  // ---- main loop: 16 units of BK=32, 2 phases each ----
  for (int u = 0; u < NU; ++u){
    int slot = u % 3;
    const unsigned short* SAb = &SA[slot*4096];
    const unsigned short* SBb = &SB[slot*8192];

    bf16x8 af0[4], af1[4], bfr[4];
    // all 12 ds_reads issued up front (DS returns in-order -> counted lgkm)
    #pragma unroll
    for (int m = 0; m < 4; ++m)
      af0[m] = *(const bf16x8*)&SAb[m*512 + rdoff];
    #pragma unroll
    for (int n = 0; n < 4; ++n)
      bfr[n] = *(const bf16x8*)&SBb[(wn*4 + n)*512 + rdoff];
    #pragma unroll
    for (int m = 0; m < 4; ++m)
      af1[m] = *(const bf16x8*)&SAb[(4 + m)*512 + rdoff];

    // stage unit u+2 into slot (u+2)%3 == (u-1)%3 (readers done at prev barrier)
    int su = u + 2;
    if (su < NU){
      int ss = su % 3;
      stage_chunk(Xn, &SA[ss*4096 + (2*wid  )*512], rowbase + (2*wid  )*16, su, prow, pcol);
      stage_chunk(Xn, &SA[ss*4096 + (2*wid+1)*512], rowbase + (2*wid+1)*16, su, prow, pcol);
      #pragma unroll
      for (int q = 0; q < 4; ++q)
        stage_chunk(Xn, &SB[ss*8192 + (4*wid+q)*512], colbase + (4*wid+q)*16, su, prow, pcol);
    }
    __builtin_amdgcn_sched_barrier(0);

    // ---- phase 0: af0 x bfr ----
    __builtin_amdgcn_s_barrier();
    asm volatile("s_waitcnt lgkmcnt(4)" ::: "memory");   // af0+bfr ready (af1 in flight)
    __builtin_amdgcn_sched_barrier(0);
    __builtin_amdgcn_s_setprio(1);
    #pragma unroll
    for (int m = 0; m < 4; ++m)
      #pragma unroll
      for (int n = 0; n < 4; ++n)
        acc[m][n] = __builtin_amdgcn_mfma_f32_16x16x32_bf16(af0[m], bfr[n], acc[m][n], 0, 0, 0);
    __builtin_amdgcn_s_setprio(0);

    // ---- phase 1: af1 x bfr ----
    __builtin_amdgcn_s_barrier();
    asm volatile("s_waitcnt lgkmcnt(0)" ::: "memory");
    __builtin_amdgcn_sched_barrier(0);
    __builtin_amdgcn_s_setprio(1);
    #pragma unroll
    for (int m = 0; m < 4; ++m)
      #pragma unroll
      for (int n = 0; n < 4; ++n)
        acc[4+m][n] = __builtin_amdgcn_mfma_f32_16x16x32_bf16(af1[m], bfr[n], acc[4+m][n], 0, 0, 0);
    __builtin_amdgcn_s_setprio(0);

    // ---- end of unit: publish slot u+1 ----
    if (u < NU-1){
      // ledger: outstanding = stage(u+1)[6] + stage(u+2)[6] -> retire (u+1);
      // at u == NU-2 only stage(NU-1)[6] outstanding -> full drain.
      if (u < NU-2) asm volatile("s_waitcnt vmcnt(6)" ::: "memory");
      else          asm volatile("s_waitcnt vmcnt(0)" ::: "memory");
      __builtin_amdgcn_s_barrier();
    }
  }

  // ---- epilogue: c>r predicate, exp, pos-pair, row/col partial sums ----
  float rsum[8][4];
  float csum[4] = {0.f, 0.f, 0.f, 0.f};
  #pragma unroll
  for (int m = 0; m < 8; ++m)
    #pragma unroll
    for (int rr = 0; rr < 4; ++rr) rsum[m][rr] = 0.f;

  #pragma unroll
  for (int m = 0; m < 8; ++m){
    #pragma unroll
    for (int n = 0; n < 4; ++n){
      int c = colbase + wn*64 + n*16 + l15;
      #pragma unroll
      for (int rr = 0; rr < 4; ++rr){
        int r = rowbase + m*16 + l4*4 + rr;
        float v = acc[m][n][rr];
        if (c - r == 4096){
          possim[r] = v;
          possim[c] = v;
        }
        float e = (c > r) ? __expf(v) : 0.f;
        rsum[m][rr] += e;
        csum[n]     += e;
      }
    }
  }

  // row-sums: reduce across 16 col-lanes; 4 waves combine via LDS; slot j
  #pragma unroll
  for (int m = 0; m < 8; ++m){
    #pragma unroll
    for (int rr = 0; rr < 4; ++rr){
      float s = rsum[m][rr];
      s += __shfl_xor(s, 1); s += __shfl_xor(s, 2);
      s += __shfl_xor(s, 4); s += __shfl_xor(s, 8);
      if (l15 == 0) redR[wn][m*16 + l4*4 + rr] = s;
    }
  }
  // col-sums: reduce across l4 groups; direct write; slot 32+i
  #pragma unroll
  for (int n = 0; n < 4; ++n){
    float s = csum[n];
    s += __shfl_xor(s, 16); s += __shfl_xor(s, 32);
    if (l4 == 0)
      rowsumP[(size_t)(32 + i)*8192 + colbase + wn*64 + n*16 + l15] = s;
  }
  __syncthreads();
  if (tid < 128){
    float rs = redR[0][tid] + redR[1][tid] + redR[2][tid] + redR[3][tid];
    rowsumP[(size_t)j*8192 + rowbase + tid] = rs;
  }
}

// ------------------- K3a: per-256-row (lse - pos) partials ------------------
__global__ __launch_bounds__(256) void k_lsepart(const float* __restrict__ rowsumP,
                                                 const float* __restrict__ possim,
                                                 float* __restrict__ part){
  int i = blockIdx.x*256 + threadIdx.x;
  float s = 0.f;
  #pragma unroll 8
  for (int cs = 0; cs < NSLOT; ++cs) s += rowsumP[(size_t)cs*8192 + i];
  float v = __logf(s) - possim[i];

  __shared__ float sred[4];
  int t = threadIdx.x;
  #pragma unroll
  for (int o = 32; o; o >>= 1) v += __shfl_down(v, o);
  if ((t & 63) == 0) sred[t >> 6] = v;
  __syncthreads();
  if (t == 0) part[blockIdx.x] = sred[0]+sred[1]+sred[2]+sred[3];
}

// --------------------------- K3b: final combine -----------------------------
__global__ __launch_bounds__(256) void k_final(const float* __restrict__ part,
                                               const float* __restrict__ jsd_row,
                                               float* __restrict__ out){
  int t = threadIdx.x;
  float s = (t < 32) ? part[t] : 0.f;
  float j = 0.f;
  #pragma unroll
  for (int q = 0; q < 16; ++q) j += jsd_row[t + q*256];

  __shared__ float sr[4], jr[4];
  float ss = s, jj = j;
  #pragma unroll
  for (int o = 32; o; o >>= 1){ ss += __shfl_down(ss, o); jj += __shfl_down(jj, o); }
  if ((t & 63) == 0){ sr[t >> 6] = ss; jr[t >> 6] = jj; }
  __syncthreads();
  if (t == 0){
    float base = (sr[0]+sr[1]+sr[2]+sr[3]) / (8192.f * (1.f + 1e-5f));
    float jsd  = (jr[0]+jr[1]+jr[2]+jr[3]) / 4096.f;
    out[0] = base + jsd;   // LAM = 1
  }
}

// ---------------------------------------------------------------------------
extern "C" void kernel_launch(void* const* d_in, const int* in_sizes, int n_in,
                              void* d_out, int out_size, void* d_ws, size_t ws_size,
                              hipStream_t stream) {
  const float* mu     = (const float*)d_in[0];
  const float* mu_cap = (const float*)d_in[1];
  const float* lv     = (const float*)d_in[2];
  const float* lv_cap = (const float*)d_in[3];
  float* out = (float*)d_out;

  char* w = (char*)d_ws;
  unsigned short* Xn = (unsigned short*)w;                    // 8192*512*2 = 8 MB
  float* rowsumP = (float*)(w + 8388608);                     // 96*8192*4 = 3 MB
  float* possim  = (float*)(w + 8388608 + 3145728);           // 32 KB
  float* jsd_row = (float*)(w + 8388608 + 3145728 + 32768);   // 16 KB
  float* part    = (float*)(w + 8388608 + 3145728 + 32768 + 16384); // 128 B

  hipMemsetAsync(rowsumP, 0, (size_t)NSLOT*8192*4, stream);
  k_featsjsd<<<4096, 256, 0, stream>>>(mu, mu_cap, lv, lv_cap, Xn, jsd_row);
  k_simlse  <<<1056, 256, 0, stream>>>(Xn, rowsumP, possim);
  k_lsepart <<<32,   256, 0, stream>>>(rowsumP, possim, part);
  k_final   <<<1,    256, 0, stream>>>(part, jsd_row, out);
}